// Round 8
// baseline (2553.835 us; speedup 1.0000x reference)
//
#include <hip/hip_runtime.h>

// ContrastiveGNN: 3x GCNConv(relu) + 2-layer projector MLP.
// N=100000 nodes, E=1600000 edges, IN_D=256, HID=OUT_D=64.
// Round 8: two-level bucket pipeline. Bucket = dst>>7 (128 nodes).
// Partition pass writes packed (src<<7|dstlo) with contiguous per-bucket
// runs (kills the 16x write amplification of node-level csr_fill).
// Gather: block per bucket, 128x64 fp32 accumulator in LDS, ds_add_f32.

#define BLK 256
#define BSHIFT 7
#define BNODES 128
#define MAXBUK 1024
#define EPT 64                      // edges per thread in partition/count
#define CHUNK (BLK * EPT)           // 16384 edges per block

// ---------------- degree + bucket histogram ----------------
__global__ void count_deg_kernel(const int* __restrict__ dst, int* __restrict__ deg_cnt,
                                 int* __restrict__ bucket_cnt, int E, int NBUK) {
    __shared__ int hist[MAXBUK];
    const int tid = threadIdx.x;
    for (int b = tid; b < NBUK; b += BLK) hist[b] = 0;
    __syncthreads();
    int base = blockIdx.x * CHUNK;
    for (int k = 0; k < EPT; ++k) {
        int e = base + k * BLK + tid;
        if (e < E) {
            int d = dst[e];
            atomicAdd(&deg_cnt[d], 1);
            atomicAdd(&hist[d >> BSHIFT], 1);
        }
    }
    __syncthreads();
    for (int b = tid; b < NBUK; b += BLK)
        if (hist[b]) atomicAdd(&bucket_cnt[b], hist[b]);
}

__global__ void deg_finalize_kernel(const int* __restrict__ deg_cnt,
                                    float* __restrict__ deg_rs, int N) {
    int i = blockIdx.x * BLK + threadIdx.x;
    if (i < N) deg_rs[i] = rsqrtf((float)deg_cnt[i] + 1.0f);   // +1 self loop
}

// ---------------- single-block exclusive scan over buckets ----------------
__global__ void bucket_scan_kernel(const int* __restrict__ cnt, int* __restrict__ bucket_start,
                                   int* __restrict__ g_cursor, int NBUK, int E) {
    __shared__ int ts[BLK];
    const int tid = threadIdx.x;
    int tb = tid * 4;
    int v[4];
    int mySum = 0;
#pragma unroll
    for (int j = 0; j < 4; ++j) {
        int g = tb + j;
        v[j] = (g < NBUK) ? cnt[g] : 0;
        mySum += v[j];
    }
    ts[tid] = mySum;
    __syncthreads();
    for (int off = 1; off < BLK; off <<= 1) {
        int t = (tid >= off) ? ts[tid - off] : 0;
        __syncthreads();
        ts[tid] += t;
        __syncthreads();
    }
    int excl = ts[tid] - mySum;
#pragma unroll
    for (int j = 0; j < 4; ++j) {
        int g = tb + j;
        if (g < NBUK) { bucket_start[g] = excl; g_cursor[g] = excl; }
        excl += v[j];
    }
    if (tid == 0) bucket_start[NBUK] = E;
}

// ---------------- partition: bucket edges, packed src<<7|dstlo ----------------
__global__ void partition_kernel(const int* __restrict__ src, const int* __restrict__ dst,
                                 int* __restrict__ g_cursor, unsigned* __restrict__ tmp,
                                 int E, int NBUK) {
    __shared__ int hist[MAXBUK];
    __shared__ int base_[MAXBUK];
    const int tid = threadIdx.x;
    for (int b = tid; b < NBUK; b += BLK) hist[b] = 0;
    __syncthreads();
    int base = blockIdx.x * CHUNK;
    for (int k = 0; k < EPT; ++k) {
        int e = base + k * BLK + tid;
        if (e < E) atomicAdd(&hist[dst[e] >> BSHIFT], 1);
    }
    __syncthreads();
    for (int b = tid; b < NBUK; b += BLK) {
        int c = hist[b];
        base_[b] = c ? atomicAdd(&g_cursor[b], c) : 0;
        hist[b] = 0;
    }
    __syncthreads();
    for (int k = 0; k < EPT; ++k) {
        int e = base + k * BLK + tid;
        if (e < E) {
            int d  = dst[e];
            int bk = d >> BSHIFT;
            int loc = atomicAdd(&hist[bk], 1);
            tmp[base_[bk] + loc] = ((unsigned)src[e] << BSHIFT) | (unsigned)(d & (BNODES - 1));
        }
    }
}

// ---------------- LDS-staged GEMM: [N,K] x [K,64] -> [N,64] ----------------
// 256 threads = 128 rows x 2 col-halves. x chunk staged in LDS (pad-65).
// W rows via wave-uniform scalar loads.
// MODE: 0=raw, 1=bias+relu, 2=bias, 3=scale rows by scale[row] (deg_rs)
template <int K, int MODE>
__global__ __launch_bounds__(256) void gemm_lds_kernel(const float* __restrict__ x,
                                                       const float* __restrict__ W,
                                                       const float* __restrict__ b,
                                                       const float* __restrict__ scale,
                                                       float* __restrict__ out, int N) {
    constexpr int KC = 64;   // k-chunk
    __shared__ float xs[128 * 65];   // 33.3 KB
    const int tid  = threadIdx.x;
    const int row  = tid & 127;
    const int half = __builtin_amdgcn_readfirstlane(threadIdx.x >> 7);  // 0/1, wave-uniform
    const int row0 = blockIdx.x * 128;

    float acc[32];
#pragma unroll
    for (int c = 0; c < 32; ++c) acc[c] = 0.f;

    for (int kc = 0; kc < K; kc += KC) {
        __syncthreads();
#pragma unroll
        for (int i = 0; i < 8; ++i) {
            int q  = i * 256 + tid;
            int r  = q >> 4;
            int j4 = q & 15;
            int gr = row0 + r; if (gr >= N) gr = N - 1;
            const float4 v = *(const float4*)(x + (size_t)gr * K + kc + j4 * 4);
            float* d = &xs[r * 65 + j4 * 4];
            d[0] = v.x; d[1] = v.y; d[2] = v.z; d[3] = v.w;
        }
        __syncthreads();

        const float* Wbase = W + (size_t)kc * 64 + half * 32;
#pragma unroll 2
        for (int k = 0; k < KC; ++k) {
            float xv = xs[row * 65 + k];
            const float* Wr = Wbase + (size_t)k * 64;   // uniform -> s_load
#pragma unroll
            for (int c = 0; c < 32; ++c) acc[c] = fmaf(xv, Wr[c], acc[c]);
        }
    }

    int gr = row0 + row;
    if (gr < N) {
        float* o = out + (size_t)gr * 64 + half * 32;
        float sc = (MODE == 3) ? scale[gr] : 1.f;
#pragma unroll
        for (int c = 0; c < 32; ++c) {
            float v = acc[c];
            if (MODE == 3)      v *= sc;
            else if (MODE != 0) v += b[half * 32 + c];
            if (MODE == 1)      v = fmaxf(v, 0.f);
            o[c] = v;
        }
    }
}

// ---------------- bucket gather: block per bucket, LDS accumulator ----------------
// h is pre-scaled by deg_rs. acc[dlo][f] = h[node] (self) + sum h[src].
// out = relu(acc * drs[node] + b). Edges packed: src<<7 | dstlo.
__global__ __launch_bounds__(256) void bucket_gather_kernel(const float* __restrict__ h,
                                                            const unsigned* __restrict__ tmp,
                                                            const int* __restrict__ bucket_start,
                                                            const float* __restrict__ deg_rs,
                                                            const float* __restrict__ bias,
                                                            float* __restrict__ out, int N) {
    __shared__ float acc[BNODES * 64];   // 32 KB
    const int tid   = threadIdx.x;
    const int bk    = blockIdx.x;
    const int node0 = bk << BSHIFT;

    // init with self-loop rows (coalesced)
#pragma unroll
    for (int i = tid; i < BNODES * 64; i += BLK) {
        int node = node0 + (i >> 6);
        acc[i] = (node < N) ? h[(size_t)node * 64 + (i & 63)] : 0.f;
    }
    __syncthreads();

    const int startE = bucket_start[bk];
    const int endE   = bucket_start[bk + 1];
    const int lane   = tid & 63;
    const int wid    = tid >> 6;

    for (int g0 = startE + wid * 4; g0 < endE; g0 += 16) {
        int n = endE - g0; if (n > 4) n = 4;
        unsigned ep[4];
        float    hv[4];
#pragma unroll
        for (int t = 0; t < 4; ++t) if (t < n) ep[t] = tmp[g0 + t];
#pragma unroll
        for (int t = 0; t < 4; ++t) if (t < n) hv[t] = h[(size_t)(ep[t] >> BSHIFT) * 64 + lane];
#pragma unroll
        for (int t = 0; t < 4; ++t) if (t < n)
            atomicAdd(&acc[((ep[t] & (BNODES - 1)) << 6) + lane], hv[t]);
    }
    __syncthreads();

    // fused epilogue
#pragma unroll
    for (int i = tid; i < BNODES * 64; i += BLK) {
        int node = node0 + (i >> 6);
        if (node < N)
            out[(size_t)node * 64 + (i & 63)] =
                fmaxf(fmaf(acc[i], deg_rs[node], bias[i & 63]), 0.f);
    }
}

extern "C" void kernel_launch(void* const* d_in, const int* in_sizes, int n_in,
                              void* d_out, int out_size, void* d_ws, size_t ws_size,
                              hipStream_t stream) {
    const float* x   = (const float*)d_in[0];
    const float* W1  = (const float*)d_in[1];
    const float* b1  = (const float*)d_in[2];
    const float* W2  = (const float*)d_in[3];
    const float* b2  = (const float*)d_in[4];
    const float* W3  = (const float*)d_in[5];
    const float* b3  = (const float*)d_in[6];
    const float* Pw1 = (const float*)d_in[7];
    const float* Pb1 = (const float*)d_in[8];
    const float* Pw2 = (const float*)d_in[9];
    const float* Pb2 = (const float*)d_in[10];
    const int*   ei  = (const int*)d_in[11];

    const int N = in_sizes[0] / 256;
    const int E = in_sizes[11] / 2;
    const int* src = ei;
    const int* dst = ei + E;
    const int NBUK = (N + BNODES - 1) >> BSHIFT;   // 782

    // workspace layout (all 4-byte types)
    char* p = (char*)d_ws;
    float*    deg_rs       = (float*)p;     p += (size_t)N * 4;
    float*    X            = (float*)p;     p += (size_t)N * 64 * 4;
    float*    H            = (float*)p;     p += (size_t)N * 64 * 4;
    int*      deg_cnt      = (int*)p;       p += (size_t)N * 4;
    int*      bucket_cnt   = (int*)p;       p += (size_t)MAXBUK * 4;
    int*      bucket_start = (int*)p;       p += (size_t)(MAXBUK + 1) * 4;
    int*      g_cursor     = (int*)p;       p += (size_t)MAXBUK * 4;
    unsigned* tmp          = (unsigned*)p;  p += (size_t)E * 4;

    const int gNode  = (N + BLK - 1) / BLK;
    const int gGemm  = (N + 127) / 128;
    const int gChunk = (E + CHUNK - 1) / CHUNK;   // 98

    // ---- degree + bucket build ----
    hipMemsetAsync(deg_cnt, 0, (size_t)N * sizeof(int), stream);
    hipMemsetAsync(bucket_cnt, 0, (size_t)MAXBUK * sizeof(int), stream);
    count_deg_kernel<<<gChunk, BLK, 0, stream>>>(dst, deg_cnt, bucket_cnt, E, NBUK);
    deg_finalize_kernel<<<gNode, BLK, 0, stream>>>(deg_cnt, deg_rs, N);
    bucket_scan_kernel<<<1, BLK, 0, stream>>>(bucket_cnt, bucket_start, g_cursor, NBUK, E);
    partition_kernel<<<gChunk, BLK, 0, stream>>>(src, dst, g_cursor, tmp, E, NBUK);

    // ---- layer 1 ----
    gemm_lds_kernel<256, 3><<<gGemm, BLK, 0, stream>>>(x, W1, nullptr, deg_rs, H, N);
    bucket_gather_kernel<<<NBUK, BLK, 0, stream>>>(H, tmp, bucket_start, deg_rs, b1, X, N);

    // ---- layer 2 ----
    gemm_lds_kernel<64, 3><<<gGemm, BLK, 0, stream>>>(X, W2, nullptr, deg_rs, H, N);
    bucket_gather_kernel<<<NBUK, BLK, 0, stream>>>(H, tmp, bucket_start, deg_rs, b2, X, N);

    // ---- layer 3 ----
    gemm_lds_kernel<64, 3><<<gGemm, BLK, 0, stream>>>(X, W3, nullptr, deg_rs, H, N);
    bucket_gather_kernel<<<NBUK, BLK, 0, stream>>>(H, tmp, bucket_start, deg_rs, b3, X, N);

    // ---- projector ----
    gemm_lds_kernel<64, 1><<<gGemm, BLK, 0, stream>>>(X, Pw1, Pb1, nullptr, H, N);
    gemm_lds_kernel<64, 2><<<gGemm, BLK, 0, stream>>>(H, Pw2, Pb2, nullptr, (float*)d_out, N);
}

// Round 9
// 664.929 us; speedup vs baseline: 3.8408x; 3.8408x over previous
//
#include <hip/hip_runtime.h>

// ContrastiveGNN: 3x GCNConv(relu) + 2-layer projector MLP.
// N=100000 nodes, E=1600000 edges, IN_D=256, HID=OUT_D=64.
// Round 9: bucket partition used ONLY to build a node-sorted CSR with
// write-local passes (no node-level random atomics anywhere in the build).
// Aggregation reverts to the proven per-node wave gather (25000 blocks).

#define BLK 256
#define BSHIFT 7
#define BNODES 128
#define MAXBUK 1024
#define EPT 64                      // edges per thread in count/partition
#define CHUNK (BLK * EPT)           // 16384 edges per block

// ---------------- bucket histogram (LDS, flushed once) ----------------
__global__ __launch_bounds__(256) void bucket_count_kernel(const int* __restrict__ dst,
                                                           int* __restrict__ bucket_cnt,
                                                           int E, int NBUK) {
    __shared__ int hist[MAXBUK];
    const int tid = threadIdx.x;
    for (int b = tid; b < NBUK; b += BLK) hist[b] = 0;
    __syncthreads();
    int base = blockIdx.x * CHUNK;
    for (int k = 0; k < EPT; ++k) {
        int e = base + k * BLK + tid;
        if (e < E) atomicAdd(&hist[dst[e] >> BSHIFT], 1);
    }
    __syncthreads();
    for (int b = tid; b < NBUK; b += BLK)
        if (hist[b]) atomicAdd(&bucket_cnt[b], hist[b]);
}

// ---------------- single-block exclusive scan over buckets ----------------
__global__ __launch_bounds__(256) void bucket_scan_kernel(const int* __restrict__ cnt,
                                                          int* __restrict__ bucket_start,
                                                          int* __restrict__ g_cursor,
                                                          int* __restrict__ rowptr,
                                                          int NBUK, int N, int E) {
    __shared__ int ts[BLK];
    const int tid = threadIdx.x;
    int tb = tid * 4;
    int v[4];
    int mySum = 0;
#pragma unroll
    for (int j = 0; j < 4; ++j) {
        int g = tb + j;
        v[j] = (g < NBUK) ? cnt[g] : 0;
        mySum += v[j];
    }
    ts[tid] = mySum;
    __syncthreads();
    for (int off = 1; off < BLK; off <<= 1) {
        int t = (tid >= off) ? ts[tid - off] : 0;
        __syncthreads();
        ts[tid] += t;
        __syncthreads();
    }
    int excl = ts[tid] - mySum;
#pragma unroll
    for (int j = 0; j < 4; ++j) {
        int g = tb + j;
        if (g < NBUK) { bucket_start[g] = excl; g_cursor[g] = excl; }
        excl += v[j];
    }
    if (tid == 0) { bucket_start[NBUK] = E; rowptr[N] = E; }
}

// ---------------- partition: bucket edges, packed src<<7|dstlo ----------------
__global__ __launch_bounds__(256) void partition_kernel(const int* __restrict__ src,
                                                        const int* __restrict__ dst,
                                                        int* __restrict__ g_cursor,
                                                        unsigned* __restrict__ tmp,
                                                        int E, int NBUK) {
    __shared__ int hist[MAXBUK];
    __shared__ int base_[MAXBUK];
    const int tid = threadIdx.x;
    for (int b = tid; b < NBUK; b += BLK) hist[b] = 0;
    __syncthreads();
    int base = blockIdx.x * CHUNK;
    for (int k = 0; k < EPT; ++k) {
        int e = base + k * BLK + tid;
        if (e < E) atomicAdd(&hist[dst[e] >> BSHIFT], 1);
    }
    __syncthreads();
    for (int b = tid; b < NBUK; b += BLK) {
        int c = hist[b];
        base_[b] = c ? atomicAdd(&g_cursor[b], c) : 0;
        hist[b] = 0;
    }
    __syncthreads();
    for (int k = 0; k < EPT; ++k) {
        int e = base + k * BLK + tid;
        if (e < E) {
            int d  = dst[e];
            int bk = d >> BSHIFT;
            int loc = atomicAdd(&hist[bk], 1);
            tmp[base_[bk] + loc] = ((unsigned)src[e] << BSHIFT) | (unsigned)(d & (BNODES - 1));
        }
    }
}

// ---------------- per-bucket CSR finalize ----------------
// One block per bucket: LDS histogram over 128 local nodes -> scan ->
// rowptr, deg_rs, and node-sorted csr_src (writes confined to an 8KB window).
__global__ __launch_bounds__(256) void bucket_csr_kernel(const unsigned* __restrict__ tmp,
                                                         const int* __restrict__ bucket_start,
                                                         int* __restrict__ rowptr,
                                                         float* __restrict__ deg_rs,
                                                         int* __restrict__ csr_src, int N) {
    __shared__ int hist[BNODES];
    __shared__ int sc[BNODES];
    __shared__ int cur[BNODES];
    const int tid   = threadIdx.x;
    const int bk    = blockIdx.x;
    const int node0 = bk << BSHIFT;
    const int beg = bucket_start[bk], end = bucket_start[bk + 1];

    if (tid < BNODES) hist[tid] = 0;
    __syncthreads();
    for (int i = beg + tid; i < end; i += BLK)
        atomicAdd(&hist[tmp[i] & (BNODES - 1)], 1);
    __syncthreads();

    if (tid < BNODES) sc[tid] = hist[tid];
    __syncthreads();
    for (int off = 1; off < BNODES; off <<= 1) {
        int t = (tid < BNODES && tid >= off) ? sc[tid - off] : 0;
        __syncthreads();
        if (tid < BNODES) sc[tid] += t;
        __syncthreads();
    }
    if (tid < BNODES) {
        int node = node0 + tid;
        if (node < N) {
            int start = beg + sc[tid] - hist[tid];   // exclusive
            rowptr[node] = start;
            cur[tid]     = start;
            deg_rs[node] = rsqrtf((float)hist[tid] + 1.0f);   // +1 self loop
        }
    }
    __syncthreads();

    for (int i = beg + tid; i < end; i += BLK) {
        unsigned pk = tmp[i];
        int pos = atomicAdd(&cur[pk & (BNODES - 1)], 1);
        csr_src[pos] = (int)(pk >> BSHIFT);
    }
}

// ---------------- LDS-staged GEMM: [N,K] x [K,64] -> [N,64] ----------------
// 256 threads = 128 rows x 2 col-halves. x chunk staged in LDS (pad-65).
// W rows via wave-uniform scalar loads.
// MODE: 0=raw, 1=bias+relu, 2=bias, 3=scale rows by scale[row] (deg_rs)
template <int K, int MODE>
__global__ __launch_bounds__(256) void gemm_lds_kernel(const float* __restrict__ x,
                                                       const float* __restrict__ W,
                                                       const float* __restrict__ b,
                                                       const float* __restrict__ scale,
                                                       float* __restrict__ out, int N) {
    constexpr int KC = 64;   // k-chunk
    __shared__ float xs[128 * 65];   // 33.3 KB
    const int tid  = threadIdx.x;
    const int row  = tid & 127;
    const int half = __builtin_amdgcn_readfirstlane(threadIdx.x >> 7);  // 0/1, wave-uniform
    const int row0 = blockIdx.x * 128;

    float acc[32];
#pragma unroll
    for (int c = 0; c < 32; ++c) acc[c] = 0.f;

    for (int kc = 0; kc < K; kc += KC) {
        __syncthreads();
#pragma unroll
        for (int i = 0; i < 8; ++i) {
            int q  = i * 256 + tid;
            int r  = q >> 4;
            int j4 = q & 15;
            int gr = row0 + r; if (gr >= N) gr = N - 1;
            const float4 v = *(const float4*)(x + (size_t)gr * K + kc + j4 * 4);
            float* d = &xs[r * 65 + j4 * 4];
            d[0] = v.x; d[1] = v.y; d[2] = v.z; d[3] = v.w;
        }
        __syncthreads();

        const float* Wbase = W + (size_t)kc * 64 + half * 32;
#pragma unroll 2
        for (int k = 0; k < KC; ++k) {
            float xv = xs[row * 65 + k];
            const float* Wr = Wbase + (size_t)k * 64;   // uniform -> s_load
#pragma unroll
            for (int c = 0; c < 32; ++c) acc[c] = fmaf(xv, Wr[c], acc[c]);
        }
    }

    int gr = row0 + row;
    if (gr < N) {
        float* o = out + (size_t)gr * 64 + half * 32;
        float sc = (MODE == 3) ? scale[gr] : 1.f;
#pragma unroll
        for (int c = 0; c < 32; ++c) {
            float v = acc[c];
            if (MODE == 3)      v *= sc;
            else if (MODE != 0) v += b[half * 32 + c];
            if (MODE == 1)      v = fmaxf(v, 0.f);
            o[c] = v;
        }
    }
}

// ---------------- gather-aggregate + fused epilogue ----------------
// h is pre-scaled by deg_rs (GEMM MODE 3). One wave per node, lane = feature.
// out = relu(drs[d] * (h[d] + sum h[src]) + b)
__global__ void gcn_gather_kernel(const float* __restrict__ h,
                                  const int* __restrict__ rowptr,
                                  const int* __restrict__ csr_src,
                                  const float* __restrict__ deg_rs,
                                  const float* __restrict__ b,
                                  float* __restrict__ out, int N) {
    int node = blockIdx.x * 4 + (threadIdx.x >> 6);
    int f    = threadIdx.x & 63;
    if (node >= N) return;
    int beg = rowptr[node], end = rowptr[node + 1];
    float acc = h[(size_t)node * 64 + f];   // self loop (h pre-scaled)
    int i = beg;
    for (; i + 4 <= end; i += 4) {
        int s0 = csr_src[i],     s1 = csr_src[i + 1];
        int s2 = csr_src[i + 2], s3 = csr_src[i + 3];
        acc += h[(size_t)s0 * 64 + f];
        acc += h[(size_t)s1 * 64 + f];
        acc += h[(size_t)s2 * 64 + f];
        acc += h[(size_t)s3 * 64 + f];
    }
    for (; i < end; ++i) acc += h[(size_t)csr_src[i] * 64 + f];
    out[(size_t)node * 64 + f] = fmaxf(fmaf(acc, deg_rs[node], b[f]), 0.f);
}

extern "C" void kernel_launch(void* const* d_in, const int* in_sizes, int n_in,
                              void* d_out, int out_size, void* d_ws, size_t ws_size,
                              hipStream_t stream) {
    const float* x   = (const float*)d_in[0];
    const float* W1  = (const float*)d_in[1];
    const float* b1  = (const float*)d_in[2];
    const float* W2  = (const float*)d_in[3];
    const float* b2  = (const float*)d_in[4];
    const float* W3  = (const float*)d_in[5];
    const float* b3  = (const float*)d_in[6];
    const float* Pw1 = (const float*)d_in[7];
    const float* Pb1 = (const float*)d_in[8];
    const float* Pw2 = (const float*)d_in[9];
    const float* Pb2 = (const float*)d_in[10];
    const int*   ei  = (const int*)d_in[11];

    const int N = in_sizes[0] / 256;
    const int E = in_sizes[11] / 2;
    const int* src = ei;
    const int* dst = ei + E;
    const int NBUK = (N + BNODES - 1) >> BSHIFT;   // 782

    // workspace layout (all 4-byte types)
    char* p = (char*)d_ws;
    float*    deg_rs       = (float*)p;     p += (size_t)N * 4;
    float*    X            = (float*)p;     p += (size_t)N * 64 * 4;
    float*    H            = (float*)p;     p += (size_t)N * 64 * 4;
    int*      bucket_cnt   = (int*)p;       p += (size_t)MAXBUK * 4;
    int*      bucket_start = (int*)p;       p += (size_t)(MAXBUK + 1) * 4;
    int*      g_cursor     = (int*)p;       p += (size_t)MAXBUK * 4;
    int*      rowptr       = (int*)p;       p += ((size_t)N + 1) * 4;
    int*      csr_src      = (int*)p;       p += (size_t)E * 4;
    unsigned* tmp          = (unsigned*)p;  p += (size_t)E * 4;

    const int gRows  = (N + 3) / 4;               // gather: 4 nodes/block
    const int gGemm  = (N + 127) / 128;           // gemm: 128 rows/block
    const int gChunk = (E + CHUNK - 1) / CHUNK;   // 98

    // ---- CSR build (all write-local, no node-level random atomics) ----
    hipMemsetAsync(bucket_cnt, 0, (size_t)MAXBUK * sizeof(int), stream);
    bucket_count_kernel<<<gChunk, BLK, 0, stream>>>(dst, bucket_cnt, E, NBUK);
    bucket_scan_kernel<<<1, BLK, 0, stream>>>(bucket_cnt, bucket_start, g_cursor, rowptr, NBUK, N, E);
    partition_kernel<<<gChunk, BLK, 0, stream>>>(src, dst, g_cursor, tmp, E, NBUK);
    bucket_csr_kernel<<<NBUK, BLK, 0, stream>>>(tmp, bucket_start, rowptr, deg_rs, csr_src, N);

    // ---- layer 1 ----
    gemm_lds_kernel<256, 3><<<gGemm, BLK, 0, stream>>>(x, W1, nullptr, deg_rs, H, N);
    gcn_gather_kernel<<<gRows, BLK, 0, stream>>>(H, rowptr, csr_src, deg_rs, b1, X, N);

    // ---- layer 2 ----
    gemm_lds_kernel<64, 3><<<gGemm, BLK, 0, stream>>>(X, W2, nullptr, deg_rs, H, N);
    gcn_gather_kernel<<<gRows, BLK, 0, stream>>>(H, rowptr, csr_src, deg_rs, b2, X, N);

    // ---- layer 3 ----
    gemm_lds_kernel<64, 3><<<gGemm, BLK, 0, stream>>>(X, W3, nullptr, deg_rs, H, N);
    gcn_gather_kernel<<<gRows, BLK, 0, stream>>>(H, rowptr, csr_src, deg_rs, b3, X, N);

    // ---- projector ----
    gemm_lds_kernel<64, 1><<<gGemm, BLK, 0, stream>>>(X, Pw1, Pb1, nullptr, H, N);
    gemm_lds_kernel<64, 2><<<gGemm, BLK, 0, stream>>>(H, Pw2, Pb2, nullptr, (float*)d_out, N);
}